// Round 5
// baseline (486.537 us; speedup 1.0000x reference)
//
#include <hip/hip_runtime.h>
#include <hip/hip_bf16.h>

#define NTHREADS 256

typedef unsigned int uint32;

__device__ __forceinline__ float4 bf4_to_f4(ushort4 v) {
    float4 r;
    r.x = __uint_as_float((uint32)v.x << 16);
    r.y = __uint_as_float((uint32)v.y << 16);
    r.z = __uint_as_float((uint32)v.z << 16);
    r.w = __uint_as_float((uint32)v.w << 16);
    return r;
}

// ---------------- CSR build ----------------
__global__ void hist_dst(int* degi, const int* __restrict__ ei, int nE) {
    int base = (blockIdx.x * NTHREADS + threadIdx.x) * 8;
    if (base + 7 < nE) {
        int4 d0 = *(const int4*)(ei + nE + base);
        int4 d1 = *(const int4*)(ei + nE + base + 4);
        atomicAdd(&degi[d0.x], 1);
        atomicAdd(&degi[d0.y], 1);
        atomicAdd(&degi[d0.z], 1);
        atomicAdd(&degi[d0.w], 1);
        atomicAdd(&degi[d1.x], 1);
        atomicAdd(&degi[d1.y], 1);
        atomicAdd(&degi[d1.z], 1);
        atomicAdd(&degi[d1.w], 1);
    } else {
        for (int j = 0; j < 8; j++) {
            int e = base + j;
            if (e < nE) atomicAdd(&degi[ei[nE + e]], 1);
        }
    }
}

// scan1: per-block (1024 elems) exclusive scan of degi -> row_ptr(local), block sums.
// Also computes dis[i] = rsqrt(1+deg) on the side (free).
__global__ __launch_bounds__(NTHREADS) void scan1(const int* __restrict__ degi,
                                                  int* row_ptr, int* bsums,
                                                  float* dis, int n) {
    __shared__ int part[NTHREADS];
    int t = threadIdx.x;
    int base = blockIdx.x * 1024 + t * 4;
    int v[4];
    int s = 0;
#pragma unroll
    for (int j = 0; j < 4; j++) {
        v[j] = (base + j < n) ? degi[base + j] : 0;
        s += v[j];
    }
#pragma unroll
    for (int j = 0; j < 4; j++) {
        if (base + j < n) dis[base + j] = rsqrtf(1.0f + (float)v[j]);
    }
    part[t] = s;
    __syncthreads();
    for (int off = 1; off < NTHREADS; off <<= 1) {
        int x = (t >= off) ? part[t - off] : 0;
        __syncthreads();
        part[t] += x;
        __syncthreads();
    }
    int excl = (t == 0) ? 0 : part[t - 1];
#pragma unroll
    for (int j = 0; j < 4; j++) {
        if (base + j < n) row_ptr[base + j] = excl;
        excl += v[j];
    }
    if (t == NTHREADS - 1) bsums[blockIdx.x] = part[NTHREADS - 1];
}

__global__ void scan2(int* bsums, int nb) {
    if (threadIdx.x == 0 && blockIdx.x == 0) {
        int run = 0;
        for (int i = 0; i < nb; i++) { int v = bsums[i]; bsums[i] = run; run += v; }
    }
}

__global__ void scan3(int* row_ptr, int* cursor, const int* __restrict__ bsums,
                      int n, int nE) {
    int i = blockIdx.x * NTHREADS + threadIdx.x;
    if (i < n) {
        int v = row_ptr[i] + bsums[i >> 10];
        row_ptr[i] = v;
        cursor[i] = v;
    }
    if (i == 0) row_ptr[n] = nE;
}

// ---------------- shared GEMM body: T[r][c] = bf16( dis[r] * sum_k relu?(in[r][k]) * W[k][c] ) ----------------
__device__ __forceinline__ void gemm_body(
    const float* __restrict__ in, __hip_bfloat16* __restrict__ out,
    const float* __restrict__ W, const float* __restrict__ dis,
    int n_rows, int relu_in, int row_base,
    float* sW, float* sX, float* sD) {
    int t = threadIdx.x;

    const float4* W4 = (const float4*)W;
    float4* sW4 = (float4*)sW;
#pragma unroll
    for (int i = 0; i < 4; i++) sW4[t + NTHREADS * i] = W4[t + NTHREADS * i];

    if (t < 64) {
        int r = row_base + t;
        sD[t] = (r < n_rows) ? dis[r] : 0.f;
    }

    float4* sX4 = (float4*)sX;
#pragma unroll
    for (int i = 0; i < 4; i++) {
        int idx = t + NTHREADS * i;
        int r = row_base + (idx >> 4);
        float4 v = make_float4(0.f, 0.f, 0.f, 0.f);
        if (r < n_rows) v = ((const float4*)(in + (size_t)r * 64))[idx & 15];
        if (relu_in) {
            v.x = fmaxf(v.x, 0.f); v.y = fmaxf(v.y, 0.f);
            v.z = fmaxf(v.z, 0.f); v.w = fmaxf(v.w, 0.f);
        }
        sX4[idx] = v;
    }
    __syncthreads();

    int c = t & 63;
    int r0 = t >> 6;
    float acc[16];
#pragma unroll
    for (int j = 0; j < 16; j++) acc[j] = 0.f;

    for (int k = 0; k < 64; k += 4) {
        float w0 = sW[(k + 0) * 64 + c];
        float w1 = sW[(k + 1) * 64 + c];
        float w2 = sW[(k + 2) * 64 + c];
        float w3 = sW[(k + 3) * 64 + c];
#pragma unroll
        for (int j = 0; j < 16; j++) {
            float4 xv = *(const float4*)(sX + (r0 + 4 * j) * 64 + k);  // wave-broadcast b128
            acc[j] += xv.x * w0 + xv.y * w1 + xv.z * w2 + xv.w * w3;
        }
    }

#pragma unroll
    for (int j = 0; j < 16; j++) {
        int r = row_base + r0 + 4 * j;
        if (r < n_rows) out[(size_t)r * 64 + c] = __float2bfloat16(sD[r0 + 4 * j] * acc[j]);
    }
}

// ---------------- fused: layer-0 GEMM + CSR bucket (independent work, one dispatch) ----------------
__global__ __launch_bounds__(NTHREADS) void gemm_bucket(
    const float* __restrict__ in, __hip_bfloat16* __restrict__ T,
    const float* __restrict__ W, const float* __restrict__ dis,
    const int* __restrict__ ei, int* cursor, int* __restrict__ col,
    int n_rows, int nE, int nBucketBlocks) {
    __shared__ __align__(16) float sW[64 * 64];
    __shared__ __align__(16) float sX[64 * 64];
    __shared__ float sD[64];

    if ((int)blockIdx.x < nBucketBlocks) {
        int base = (blockIdx.x * NTHREADS + threadIdx.x) * 8;
        if (base + 7 < nE) {
            int4 s0 = *(const int4*)(ei + base);
            int4 s1 = *(const int4*)(ei + base + 4);
            int4 d0 = *(const int4*)(ei + nE + base);
            int4 d1 = *(const int4*)(ei + nE + base + 4);
            int p0 = atomicAdd(&cursor[d0.x], 1);
            int p1 = atomicAdd(&cursor[d0.y], 1);
            int p2 = atomicAdd(&cursor[d0.z], 1);
            int p3 = atomicAdd(&cursor[d0.w], 1);
            int p4 = atomicAdd(&cursor[d1.x], 1);
            int p5 = atomicAdd(&cursor[d1.y], 1);
            int p6 = atomicAdd(&cursor[d1.z], 1);
            int p7 = atomicAdd(&cursor[d1.w], 1);
            col[p0] = s0.x; col[p1] = s0.y; col[p2] = s0.z; col[p3] = s0.w;
            col[p4] = s1.x; col[p5] = s1.y; col[p6] = s1.z; col[p7] = s1.w;
        } else {
            for (int j = 0; j < 8; j++) {
                int e = base + j;
                if (e < nE) {
                    int s = ei[e];
                    int d = ei[nE + e];
                    col[atomicAdd(&cursor[d], 1)] = s;
                }
            }
        }
        return;
    }

    int gb = blockIdx.x - nBucketBlocks;
    gemm_body(in, T, W, dis, n_rows, 0, gb * 64, sW, sX, sD);
}

// ---------------- standalone GEMM (layers 1,2) ----------------
__global__ __launch_bounds__(NTHREADS) void gemm64(
    const float* __restrict__ in, __hip_bfloat16* __restrict__ out,
    const float* __restrict__ W, const float* __restrict__ dis,
    int n_rows, int relu_in) {
    __shared__ __align__(16) float sW[64 * 64];
    __shared__ __align__(16) float sX[64 * 64];
    __shared__ float sD[64];
    gemm_body(in, out, W, dis, n_rows, relu_in, blockIdx.x * 64, sW, sX, sD);
}

// ---------------- GCN aggregate: out[d] = bias + dis[d]*(T'[d] + sum_in T'[s]) ----------------
// 16 lanes per node; T' is bf16, pre-scaled by dis[src]. No per-edge weights.
__global__ __launch_bounds__(NTHREADS) void gcn_aggregate(
    const __hip_bfloat16* __restrict__ T, float* __restrict__ out,
    const float* __restrict__ dis, const float* __restrict__ bias,
    const int* __restrict__ row_ptr, const int* __restrict__ col, int n) {
    int node = (blockIdx.x * NTHREADS + threadIdx.x) >> 4;
    int q = threadIdx.x & 15;
    if (node >= n) return;

    const ushort4* T4 = (const ushort4*)T;
    float4 acc = bf4_to_f4(T4[(size_t)node * 16 + q]);  // self term

    int e0 = row_ptr[node];
    int e1 = row_ptr[node + 1];
    int e = e0;
    for (; e + 3 < e1; e += 4) {
        int s0 = col[e], s1 = col[e + 1], s2 = col[e + 2], s3 = col[e + 3];
        float4 f0 = bf4_to_f4(T4[(size_t)s0 * 16 + q]);
        float4 f1 = bf4_to_f4(T4[(size_t)s1 * 16 + q]);
        float4 f2 = bf4_to_f4(T4[(size_t)s2 * 16 + q]);
        float4 f3 = bf4_to_f4(T4[(size_t)s3 * 16 + q]);
        acc.x += (f0.x + f1.x) + (f2.x + f3.x);
        acc.y += (f0.y + f1.y) + (f2.y + f3.y);
        acc.z += (f0.z + f1.z) + (f2.z + f3.z);
        acc.w += (f0.w + f1.w) + (f2.w + f3.w);
    }
    for (; e < e1; e++) {
        float4 f0 = bf4_to_f4(T4[(size_t)col[e] * 16 + q]);
        acc.x += f0.x; acc.y += f0.y; acc.z += f0.z; acc.w += f0.w;
    }

    float dn = dis[node];
    float4 b = ((const float4*)bias)[q];
    float4 o;
    o.x = b.x + dn * acc.x;
    o.y = b.y + dn * acc.y;
    o.z = b.z + dn * acc.z;
    o.w = b.w + dn * acc.w;
    ((float4*)out)[(size_t)node * 16 + q] = o;
}

// ---------------- pooling: 128 nodes/block, register run-length, global atomics ----------------
__global__ __launch_bounds__(NTHREADS) void pool_kernel(
    const float* __restrict__ h, const int* __restrict__ gid,
    float* __restrict__ pooled, int n) {
    int t = threadIdx.x;
    int q = t & 15;
    int w = t >> 4;
    int base = blockIdx.x * 128;

    float4 racc = make_float4(0.f, 0.f, 0.f, 0.f);
    int cur = -1;
#pragma unroll
    for (int i = 0; i < 8; i++) {
        int node = base + i * 16 + w;
        if (node < n) {
            int g = gid[node];
            if (g != cur) {
                if (cur >= 0) {
                    float* p = pooled + cur * 64 + q * 4;
                    if (racc.x != 0.f) atomicAdd(p + 0, racc.x);
                    if (racc.y != 0.f) atomicAdd(p + 1, racc.y);
                    if (racc.z != 0.f) atomicAdd(p + 2, racc.z);
                    if (racc.w != 0.f) atomicAdd(p + 3, racc.w);
                }
                racc = make_float4(0.f, 0.f, 0.f, 0.f);
                cur = g;
            }
            float4 v = ((const float4*)h)[(size_t)node * 16 + q];
            racc.x += fmaxf(v.x, 0.f);
            racc.y += fmaxf(v.y, 0.f);
            racc.z += fmaxf(v.z, 0.f);
            racc.w += fmaxf(v.w, 0.f);
        }
    }
    if (cur >= 0) {
        float* p = pooled + cur * 64 + q * 4;
        if (racc.x != 0.f) atomicAdd(p + 0, racc.x);
        if (racc.y != 0.f) atomicAdd(p + 1, racc.y);
        if (racc.z != 0.f) atomicAdd(p + 2, racc.z);
        if (racc.w != 0.f) atomicAdd(p + 3, racc.w);
    }
}

// ---------------- head MLP (one block) ----------------
__global__ __launch_bounds__(NTHREADS) void head_kernel(
    const float* __restrict__ pooled, const float* __restrict__ gf,
    const float* __restrict__ glob_w, const float* __restrict__ glob_b,
    const float* __restrict__ lin1_w, const float* __restrict__ lin1_b,
    const float* __restrict__ lin2_w, const float* __restrict__ lin2_b,
    const float* __restrict__ lin3_w, const float* __restrict__ lin3_b,
    const float* __restrict__ lin4_w, const float* __restrict__ lin4_b,
    float* __restrict__ out) {
    __shared__ float gx[64 * 32];
    __shared__ float zA[64 * 64];
    __shared__ float zB[64 * 64];
    int t = threadIdx.x;

    for (int i = t; i < 64 * 32; i += NTHREADS) {
        int g = i >> 5, j = i & 31;
        float acc = glob_b[j];
        for (int k = 0; k < 32; k++) acc += gf[g * 32 + k] * glob_w[k * 32 + j];
        gx[i] = fmaxf(acc, 0.f);
    }
    for (int i = t; i < 4096; i += NTHREADS) {
        int g = i >> 6, j = i & 63;
        float acc = lin1_b[j];
        for (int k = 0; k < 64; k++) acc += pooled[g * 64 + k] * lin1_w[k * 64 + j];
        zA[i] = fmaxf(acc, 0.f);
    }
    __syncthreads();
    for (int i = t; i < 4096; i += NTHREADS) {
        int g = i >> 6, j = i & 63;
        float acc = lin2_b[j];
        for (int k = 0; k < 64; k++) acc += zA[g * 64 + k] * lin2_w[k * 64 + j];
        for (int k = 0; k < 32; k++) acc += gx[g * 32 + k] * lin2_w[(64 + k) * 64 + j];
        zB[i] = fmaxf(acc, 0.f);
    }
    __syncthreads();
    for (int i = t; i < 4096; i += NTHREADS) {
        int g = i >> 6, j = i & 63;
        float acc = lin3_b[j];
        for (int k = 0; k < 64; k++) acc += zB[g * 64 + k] * lin3_w[k * 64 + j];
        zA[i] = fmaxf(acc, 0.f);
    }
    __syncthreads();
    if (t < 64) {
        float acc = lin4_b[0];
        for (int k = 0; k < 64; k++) acc += zA[t * 64 + k] * lin4_w[k];
        out[t] = acc;
    }
}

extern "C" void kernel_launch(void* const* d_in, const int* in_sizes, int n_in,
                              void* d_out, int out_size, void* d_ws, size_t ws_size,
                              hipStream_t stream) {
    const float* x      = (const float*)d_in[0];
    const float* gf     = (const float*)d_in[1];
    const float* conv_w[3] = {(const float*)d_in[2], (const float*)d_in[4], (const float*)d_in[6]};
    const float* conv_b[3] = {(const float*)d_in[3], (const float*)d_in[5], (const float*)d_in[7]};
    const float* lin1_w = (const float*)d_in[8];
    const float* lin1_b = (const float*)d_in[9];
    const float* glob_w = (const float*)d_in[10];
    const float* glob_b = (const float*)d_in[11];
    const float* lin2_w = (const float*)d_in[12];
    const float* lin2_b = (const float*)d_in[13];
    const float* lin3_w = (const float*)d_in[14];
    const float* lin3_b = (const float*)d_in[15];
    const float* lin4_w = (const float*)d_in[16];
    const float* lin4_b = (const float*)d_in[17];
    const int* ei  = (const int*)d_in[18];
    const int* gid = (const int*)d_in[19];

    const int N = in_sizes[0] / 64;   // 100000
    const int E = in_sizes[18] / 2;   // 1600000

    // workspace layout (keep every segment 16B-aligned)
    char* ws = (char*)d_ws;
    float* dis     = (float*)ws;                 ws += (size_t)N * 4;
    float* pooled  = (float*)ws;                 ws += 4096 * 4;
    __hip_bfloat16* T = (__hip_bfloat16*)ws;     ws += (size_t)N * 64 * 2;
    float* A       = (float*)ws;                 ws += (size_t)N * 64 * 4;
    int*   degi    = (int*)ws;                   ws += (size_t)N * 4;
    int*   row_ptr = (int*)ws;                   ws += ((size_t)N + 4) * 4;
    int*   cursor  = (int*)ws;                   ws += (size_t)N * 4;
    int*   col     = (int*)ws;                   ws += (size_t)E * 4;
    int*   bsums   = (int*)ws;                   ws += 512 * 4;

    const int nb_N  = (N + NTHREADS - 1) / NTHREADS;
    const int nb_E8 = (E / 8 + NTHREADS - 1) / NTHREADS;   // 8 edges/thread
    const int nb_sc = (N + 1023) / 1024;

    // ---- CSR build prefix ----
    hipMemsetAsync(degi, 0, (size_t)N * 4, stream);
    hist_dst<<<nb_E8, NTHREADS, 0, stream>>>(degi, ei, E);
    scan1<<<nb_sc, NTHREADS, 0, stream>>>(degi, row_ptr, bsums, dis, N);
    scan2<<<1, 64, 0, stream>>>(bsums, nb_sc);
    scan3<<<nb_N, NTHREADS, 0, stream>>>(row_ptr, cursor, bsums, N, E);

    const int gemm_blocks = (N + 63) / 64;
    const int agg_blocks  = (N * 16 + NTHREADS - 1) / NTHREADS;

    // layer 0 GEMM fused with bucket (independent work)
    gemm_bucket<<<nb_E8 + gemm_blocks, NTHREADS, 0, stream>>>(
        x, T, conv_w[0], dis, ei, cursor, col, N, E, nb_E8);
    gcn_aggregate<<<agg_blocks, NTHREADS, 0, stream>>>(T, A, dis, conv_b[0], row_ptr, col, N);

    // layer 1: relu(A) -> T -> A
    gemm64<<<gemm_blocks, NTHREADS, 0, stream>>>(A, T, conv_w[1], dis, N, 1);
    gcn_aggregate<<<agg_blocks, NTHREADS, 0, stream>>>(T, A, dis, conv_b[1], row_ptr, col, N);

    // layer 2: relu(A) -> T -> A
    gemm64<<<gemm_blocks, NTHREADS, 0, stream>>>(A, T, conv_w[2], dis, N, 1);
    gcn_aggregate<<<agg_blocks, NTHREADS, 0, stream>>>(T, A, dis, conv_b[2], row_ptr, col, N);

    // pooling (applies relu to conv2 output)
    hipMemsetAsync(pooled, 0, 4096 * 4, stream);
    pool_kernel<<<(N + 127) / 128, NTHREADS, 0, stream>>>(A, gid, pooled, N);

    // head MLP
    head_kernel<<<1, NTHREADS, 0, stream>>>(pooled, gf,
                                            glob_w, glob_b, lin1_w, lin1_b,
                                            lin2_w, lin2_b, lin3_w, lin3_b,
                                            lin4_w, lin4_b, (float*)d_out);
}

// Round 6
// 394.785 us; speedup vs baseline: 1.2324x; 1.2324x over previous
//
#include <hip/hip_runtime.h>
#include <hip/hip_bf16.h>

#define NTHREADS 256

typedef unsigned int uint32;

__device__ __forceinline__ float4 bf4_to_f4(ushort4 v) {
    float4 r;
    r.x = __uint_as_float((uint32)v.x << 16);
    r.y = __uint_as_float((uint32)v.y << 16);
    r.z = __uint_as_float((uint32)v.z << 16);
    r.w = __uint_as_float((uint32)v.w << 16);
    return r;
}

// ---------------- CSR build ----------------
// hist: degree count; the atomic's return value IS the edge's rank within its dst.
__global__ void hist_dst(int* degi, int* __restrict__ rank,
                         const int* __restrict__ ei, int nE) {
    int base = (blockIdx.x * NTHREADS + threadIdx.x) * 8;
    if (base + 7 < nE) {
        int4 d0 = *(const int4*)(ei + nE + base);
        int4 d1 = *(const int4*)(ei + nE + base + 4);
        int4 r0, r1;
        r0.x = atomicAdd(&degi[d0.x], 1);
        r0.y = atomicAdd(&degi[d0.y], 1);
        r0.z = atomicAdd(&degi[d0.z], 1);
        r0.w = atomicAdd(&degi[d0.w], 1);
        r1.x = atomicAdd(&degi[d1.x], 1);
        r1.y = atomicAdd(&degi[d1.y], 1);
        r1.z = atomicAdd(&degi[d1.z], 1);
        r1.w = atomicAdd(&degi[d1.w], 1);
        *(int4*)(rank + base) = r0;        // coalesced
        *(int4*)(rank + base + 4) = r1;
    } else {
        for (int j = 0; j < 8; j++) {
            int e = base + j;
            if (e < nE) rank[e] = atomicAdd(&degi[ei[nE + e]], 1);
        }
    }
}

// scan1: per-block (1024 elems) exclusive scan of degi -> row_ptr(local), block sums.
// Also computes dis[i] = rsqrt(1+deg) on the side (free).
__global__ __launch_bounds__(NTHREADS) void scan1(const int* __restrict__ degi,
                                                  int* row_ptr, int* bsums,
                                                  float* dis, int n) {
    __shared__ int part[NTHREADS];
    int t = threadIdx.x;
    int base = blockIdx.x * 1024 + t * 4;
    int v[4];
    int s = 0;
#pragma unroll
    for (int j = 0; j < 4; j++) {
        v[j] = (base + j < n) ? degi[base + j] : 0;
        s += v[j];
    }
#pragma unroll
    for (int j = 0; j < 4; j++) {
        if (base + j < n) dis[base + j] = rsqrtf(1.0f + (float)v[j]);
    }
    part[t] = s;
    __syncthreads();
    for (int off = 1; off < NTHREADS; off <<= 1) {
        int x = (t >= off) ? part[t - off] : 0;
        __syncthreads();
        part[t] += x;
        __syncthreads();
    }
    int excl = (t == 0) ? 0 : part[t - 1];
#pragma unroll
    for (int j = 0; j < 4; j++) {
        if (base + j < n) row_ptr[base + j] = excl;
        excl += v[j];
    }
    if (t == NTHREADS - 1) bsums[blockIdx.x] = part[NTHREADS - 1];
}

__global__ void scan2(int* bsums, int nb) {
    if (threadIdx.x == 0 && blockIdx.x == 0) {
        int run = 0;
        for (int i = 0; i < nb; i++) { int v = bsums[i]; bsums[i] = run; run += v; }
    }
}

__global__ void scan3(int* row_ptr, const int* __restrict__ bsums, int n, int nE) {
    int i = blockIdx.x * NTHREADS + threadIdx.x;
    if (i < n) row_ptr[i] += bsums[i >> 10];
    if (i == 0) row_ptr[n] = nE;
}

// bucket: no atomics — position = row_ptr[dst] (L2-cached gather) + rank (precomputed)
__global__ void bucket(const int* __restrict__ ei, const int* __restrict__ rank,
                       const int* __restrict__ row_ptr, int* __restrict__ col, int nE) {
    int base = (blockIdx.x * NTHREADS + threadIdx.x) * 8;
    if (base + 7 < nE) {
        int4 s0 = *(const int4*)(ei + base);
        int4 s1 = *(const int4*)(ei + base + 4);
        int4 d0 = *(const int4*)(ei + nE + base);
        int4 d1 = *(const int4*)(ei + nE + base + 4);
        int4 r0 = *(const int4*)(rank + base);
        int4 r1 = *(const int4*)(rank + base + 4);
        col[row_ptr[d0.x] + r0.x] = s0.x;
        col[row_ptr[d0.y] + r0.y] = s0.y;
        col[row_ptr[d0.z] + r0.z] = s0.z;
        col[row_ptr[d0.w] + r0.w] = s0.w;
        col[row_ptr[d1.x] + r1.x] = s1.x;
        col[row_ptr[d1.y] + r1.y] = s1.y;
        col[row_ptr[d1.z] + r1.z] = s1.z;
        col[row_ptr[d1.w] + r1.w] = s1.w;
    } else {
        for (int j = 0; j < 8; j++) {
            int e = base + j;
            if (e < nE) col[row_ptr[ei[nE + e]] + rank[e]] = ei[e];
        }
    }
}

// ---------------- GEMM: T[r][c] = bf16( dis[r] * sum_k relu?(in[r][k]) * W[k][c] ) ----------------
__global__ __launch_bounds__(NTHREADS) void gemm64(
    const float* __restrict__ in, __hip_bfloat16* __restrict__ out,
    const float* __restrict__ W, const float* __restrict__ dis,
    int n_rows, int relu_in) {
    __shared__ __align__(16) float sW[64 * 64];
    __shared__ __align__(16) float sX[64 * 64];
    __shared__ float sD[64];
    int t = threadIdx.x;
    int row_base = blockIdx.x * 64;

    const float4* W4 = (const float4*)W;
    float4* sW4 = (float4*)sW;
#pragma unroll
    for (int i = 0; i < 4; i++) sW4[t + NTHREADS * i] = W4[t + NTHREADS * i];

    if (t < 64) {
        int r = row_base + t;
        sD[t] = (r < n_rows) ? dis[r] : 0.f;
    }

    float4* sX4 = (float4*)sX;
#pragma unroll
    for (int i = 0; i < 4; i++) {
        int idx = t + NTHREADS * i;
        int r = row_base + (idx >> 4);
        float4 v = make_float4(0.f, 0.f, 0.f, 0.f);
        if (r < n_rows) v = ((const float4*)(in + (size_t)r * 64))[idx & 15];
        if (relu_in) {
            v.x = fmaxf(v.x, 0.f); v.y = fmaxf(v.y, 0.f);
            v.z = fmaxf(v.z, 0.f); v.w = fmaxf(v.w, 0.f);
        }
        sX4[idx] = v;
    }
    __syncthreads();

    int c = t & 63;
    int r0 = t >> 6;
    float acc[16];
#pragma unroll
    for (int j = 0; j < 16; j++) acc[j] = 0.f;

    for (int k = 0; k < 64; k += 4) {
        float w0 = sW[(k + 0) * 64 + c];
        float w1 = sW[(k + 1) * 64 + c];
        float w2 = sW[(k + 2) * 64 + c];
        float w3 = sW[(k + 3) * 64 + c];
#pragma unroll
        for (int j = 0; j < 16; j++) {
            float4 xv = *(const float4*)(sX + (r0 + 4 * j) * 64 + k);
            acc[j] += xv.x * w0 + xv.y * w1 + xv.z * w2 + xv.w * w3;
        }
    }

#pragma unroll
    for (int j = 0; j < 16; j++) {
        int r = row_base + r0 + 4 * j;
        if (r < n_rows) out[(size_t)r * 64 + c] = __float2bfloat16(sD[r0 + 4 * j] * acc[j]);
    }
}

// ---------------- GCN aggregate: out[d] = bias + dis[d]*(T'[d] + sum_in T'[s]) ----------------
__global__ __launch_bounds__(NTHREADS) void gcn_aggregate(
    const __hip_bfloat16* __restrict__ T, float* __restrict__ out,
    const float* __restrict__ dis, const float* __restrict__ bias,
    const int* __restrict__ row_ptr, const int* __restrict__ col, int n) {
    int node = (blockIdx.x * NTHREADS + threadIdx.x) >> 4;
    int q = threadIdx.x & 15;
    if (node >= n) return;

    const ushort4* T4 = (const ushort4*)T;
    float4 acc = bf4_to_f4(T4[(size_t)node * 16 + q]);  // self term

    int e0 = row_ptr[node];
    int e1 = row_ptr[node + 1];
    int e = e0;
    for (; e + 3 < e1; e += 4) {
        int s0 = col[e], s1 = col[e + 1], s2 = col[e + 2], s3 = col[e + 3];
        float4 f0 = bf4_to_f4(T4[(size_t)s0 * 16 + q]);
        float4 f1 = bf4_to_f4(T4[(size_t)s1 * 16 + q]);
        float4 f2 = bf4_to_f4(T4[(size_t)s2 * 16 + q]);
        float4 f3 = bf4_to_f4(T4[(size_t)s3 * 16 + q]);
        acc.x += (f0.x + f1.x) + (f2.x + f3.x);
        acc.y += (f0.y + f1.y) + (f2.y + f3.y);
        acc.z += (f0.z + f1.z) + (f2.z + f3.z);
        acc.w += (f0.w + f1.w) + (f2.w + f3.w);
    }
    for (; e < e1; e++) {
        float4 f0 = bf4_to_f4(T4[(size_t)col[e] * 16 + q]);
        acc.x += f0.x; acc.y += f0.y; acc.z += f0.z; acc.w += f0.w;
    }

    float dn = dis[node];
    float4 b = ((const float4*)bias)[q];
    float4 o;
    o.x = b.x + dn * acc.x;
    o.y = b.y + dn * acc.y;
    o.z = b.z + dn * acc.z;
    o.w = b.w + dn * acc.w;
    ((float4*)out)[(size_t)node * 16 + q] = o;
}

// ---------------- pooling: 128 nodes/block, register run-length, global atomics ----------------
__global__ __launch_bounds__(NTHREADS) void pool_kernel(
    const float* __restrict__ h, const int* __restrict__ gid,
    float* __restrict__ pooled, int n) {
    int t = threadIdx.x;
    int q = t & 15;
    int w = t >> 4;
    int base = blockIdx.x * 128;

    float4 racc = make_float4(0.f, 0.f, 0.f, 0.f);
    int cur = -1;
#pragma unroll
    for (int i = 0; i < 8; i++) {
        int node = base + i * 16 + w;
        if (node < n) {
            int g = gid[node];
            if (g != cur) {
                if (cur >= 0) {
                    float* p = pooled + cur * 64 + q * 4;
                    if (racc.x != 0.f) atomicAdd(p + 0, racc.x);
                    if (racc.y != 0.f) atomicAdd(p + 1, racc.y);
                    if (racc.z != 0.f) atomicAdd(p + 2, racc.z);
                    if (racc.w != 0.f) atomicAdd(p + 3, racc.w);
                }
                racc = make_float4(0.f, 0.f, 0.f, 0.f);
                cur = g;
            }
            float4 v = ((const float4*)h)[(size_t)node * 16 + q];
            racc.x += fmaxf(v.x, 0.f);
            racc.y += fmaxf(v.y, 0.f);
            racc.z += fmaxf(v.z, 0.f);
            racc.w += fmaxf(v.w, 0.f);
        }
    }
    if (cur >= 0) {
        float* p = pooled + cur * 64 + q * 4;
        if (racc.x != 0.f) atomicAdd(p + 0, racc.x);
        if (racc.y != 0.f) atomicAdd(p + 1, racc.y);
        if (racc.z != 0.f) atomicAdd(p + 2, racc.z);
        if (racc.w != 0.f) atomicAdd(p + 3, racc.w);
    }
}

// ---------------- head MLP (one block) ----------------
__global__ __launch_bounds__(NTHREADS) void head_kernel(
    const float* __restrict__ pooled, const float* __restrict__ gf,
    const float* __restrict__ glob_w, const float* __restrict__ glob_b,
    const float* __restrict__ lin1_w, const float* __restrict__ lin1_b,
    const float* __restrict__ lin2_w, const float* __restrict__ lin2_b,
    const float* __restrict__ lin3_w, const float* __restrict__ lin3_b,
    const float* __restrict__ lin4_w, const float* __restrict__ lin4_b,
    float* __restrict__ out) {
    __shared__ float gx[64 * 32];
    __shared__ float zA[64 * 64];
    __shared__ float zB[64 * 64];
    int t = threadIdx.x;

    for (int i = t; i < 64 * 32; i += NTHREADS) {
        int g = i >> 5, j = i & 31;
        float acc = glob_b[j];
        for (int k = 0; k < 32; k++) acc += gf[g * 32 + k] * glob_w[k * 32 + j];
        gx[i] = fmaxf(acc, 0.f);
    }
    for (int i = t; i < 4096; i += NTHREADS) {
        int g = i >> 6, j = i & 63;
        float acc = lin1_b[j];
        for (int k = 0; k < 64; k++) acc += pooled[g * 64 + k] * lin1_w[k * 64 + j];
        zA[i] = fmaxf(acc, 0.f);
    }
    __syncthreads();
    for (int i = t; i < 4096; i += NTHREADS) {
        int g = i >> 6, j = i & 63;
        float acc = lin2_b[j];
        for (int k = 0; k < 64; k++) acc += zA[g * 64 + k] * lin2_w[k * 64 + j];
        for (int k = 0; k < 32; k++) acc += gx[g * 32 + k] * lin2_w[(64 + k) * 64 + j];
        zB[i] = fmaxf(acc, 0.f);
    }
    __syncthreads();
    for (int i = t; i < 4096; i += NTHREADS) {
        int g = i >> 6, j = i & 63;
        float acc = lin3_b[j];
        for (int k = 0; k < 64; k++) acc += zB[g * 64 + k] * lin3_w[k * 64 + j];
        zA[i] = fmaxf(acc, 0.f);
    }
    __syncthreads();
    if (t < 64) {
        float acc = lin4_b[0];
        for (int k = 0; k < 64; k++) acc += zA[t * 64 + k] * lin4_w[k];
        out[t] = acc;
    }
}

extern "C" void kernel_launch(void* const* d_in, const int* in_sizes, int n_in,
                              void* d_out, int out_size, void* d_ws, size_t ws_size,
                              hipStream_t stream) {
    const float* x      = (const float*)d_in[0];
    const float* gf     = (const float*)d_in[1];
    const float* conv_w[3] = {(const float*)d_in[2], (const float*)d_in[4], (const float*)d_in[6]};
    const float* conv_b[3] = {(const float*)d_in[3], (const float*)d_in[5], (const float*)d_in[7]};
    const float* lin1_w = (const float*)d_in[8];
    const float* lin1_b = (const float*)d_in[9];
    const float* glob_w = (const float*)d_in[10];
    const float* glob_b = (const float*)d_in[11];
    const float* lin2_w = (const float*)d_in[12];
    const float* lin2_b = (const float*)d_in[13];
    const float* lin3_w = (const float*)d_in[14];
    const float* lin3_b = (const float*)d_in[15];
    const float* lin4_w = (const float*)d_in[16];
    const float* lin4_b = (const float*)d_in[17];
    const int* ei  = (const int*)d_in[18];
    const int* gid = (const int*)d_in[19];

    const int N = in_sizes[0] / 64;   // 100000
    const int E = in_sizes[18] / 2;   // 1600000

    // workspace layout (keep every segment 16B-aligned)
    char* ws = (char*)d_ws;
    float* dis     = (float*)ws;                 ws += (size_t)N * 4;
    float* pooled  = (float*)ws;                 ws += 4096 * 4;
    __hip_bfloat16* T = (__hip_bfloat16*)ws;     ws += (size_t)N * 64 * 2;
    float* A       = (float*)ws;                 ws += (size_t)N * 64 * 4;
    int*   degi    = (int*)ws;                   ws += (size_t)N * 4;
    int*   row_ptr = (int*)ws;                   ws += ((size_t)N + 4) * 4;
    int*   rank    = (int*)ws;                   ws += (size_t)E * 4;
    int*   col     = (int*)ws;                   ws += (size_t)E * 4;
    int*   bsums   = (int*)ws;                   ws += 512 * 4;

    const int nb_N  = (N + NTHREADS - 1) / NTHREADS;
    const int nb_E8 = (E / 8 + NTHREADS - 1) / NTHREADS;   // 8 edges/thread
    const int nb_sc = (N + 1023) / 1024;

    // ---- CSR build ----
    hipMemsetAsync(degi, 0, (size_t)N * 4, stream);
    hist_dst<<<nb_E8, NTHREADS, 0, stream>>>(degi, rank, ei, E);
    scan1<<<nb_sc, NTHREADS, 0, stream>>>(degi, row_ptr, bsums, dis, N);
    scan2<<<1, 64, 0, stream>>>(bsums, nb_sc);
    scan3<<<nb_N, NTHREADS, 0, stream>>>(row_ptr, bsums, N, E);
    bucket<<<nb_E8, NTHREADS, 0, stream>>>(ei, rank, row_ptr, col, E);

    const int gemm_blocks = (N + 63) / 64;
    const int agg_blocks  = (N * 16 + NTHREADS - 1) / NTHREADS;

    // layer 0: x -> T -> A
    gemm64<<<gemm_blocks, NTHREADS, 0, stream>>>(x, T, conv_w[0], dis, N, 0);
    gcn_aggregate<<<agg_blocks, NTHREADS, 0, stream>>>(T, A, dis, conv_b[0], row_ptr, col, N);

    // layer 1: relu(A) -> T -> A
    gemm64<<<gemm_blocks, NTHREADS, 0, stream>>>(A, T, conv_w[1], dis, N, 1);
    gcn_aggregate<<<agg_blocks, NTHREADS, 0, stream>>>(T, A, dis, conv_b[1], row_ptr, col, N);

    // layer 2: relu(A) -> T -> A
    gemm64<<<gemm_blocks, NTHREADS, 0, stream>>>(A, T, conv_w[2], dis, N, 1);
    gcn_aggregate<<<agg_blocks, NTHREADS, 0, stream>>>(T, A, dis, conv_b[2], row_ptr, col, N);

    // pooling (applies relu to conv2 output)
    hipMemsetAsync(pooled, 0, 4096 * 4, stream);
    pool_kernel<<<(N + 127) / 128, NTHREADS, 0, stream>>>(A, gid, pooled, N);

    // head MLP
    head_kernel<<<1, NTHREADS, 0, stream>>>(pooled, gf,
                                            glob_w, glob_b, lin1_w, lin1_b,
                                            lin2_w, lin2_b, lin3_w, lin3_b,
                                            lin4_w, lin4_b, (float*)d_out);
}

// Round 7
// 380.512 us; speedup vs baseline: 1.2786x; 1.0375x over previous
//
#include <hip/hip_runtime.h>
#include <hip/hip_bf16.h>

#define NTHREADS 256

typedef unsigned int uint32;

__device__ __forceinline__ float4 bf4_to_f4(ushort4 v) {
    float4 r;
    r.x = __uint_as_float((uint32)v.x << 16);
    r.y = __uint_as_float((uint32)v.y << 16);
    r.z = __uint_as_float((uint32)v.z << 16);
    r.w = __uint_as_float((uint32)v.w << 16);
    return r;
}

// ---------------- CSR build ----------------
// hist: degree count; the atomic's return value IS the edge's rank within its dst.
// 2 edges/thread -> 3125 blocks -> max occupancy for atomic latency hiding.
__global__ void hist_dst(int* degi, int* __restrict__ rank,
                         const int* __restrict__ ei, int nE) {
    int base = (blockIdx.x * NTHREADS + threadIdx.x) * 2;
    if (base + 1 < nE) {
        int2 d = *(const int2*)(ei + nE + base);
        int2 r;
        r.x = atomicAdd(&degi[d.x], 1);
        r.y = atomicAdd(&degi[d.y], 1);
        *(int2*)(rank + base) = r;
    } else if (base < nE) {
        rank[base] = atomicAdd(&degi[ei[nE + base]], 1);
    }
}

// scan1: per-block (1024 elems) exclusive scan of degi -> row_ptr(local), block sums.
// Also computes dis[i] = rsqrt(1+deg) on the side (free).
__global__ __launch_bounds__(NTHREADS) void scan1(const int* __restrict__ degi,
                                                  int* row_ptr, int* bsums,
                                                  float* dis, int n) {
    __shared__ int part[NTHREADS];
    int t = threadIdx.x;
    int base = blockIdx.x * 1024 + t * 4;
    int v[4];
    int s = 0;
#pragma unroll
    for (int j = 0; j < 4; j++) {
        v[j] = (base + j < n) ? degi[base + j] : 0;
        s += v[j];
    }
#pragma unroll
    for (int j = 0; j < 4; j++) {
        if (base + j < n) dis[base + j] = rsqrtf(1.0f + (float)v[j]);
    }
    part[t] = s;
    __syncthreads();
    for (int off = 1; off < NTHREADS; off <<= 1) {
        int x = (t >= off) ? part[t - off] : 0;
        __syncthreads();
        part[t] += x;
        __syncthreads();
    }
    int excl = (t == 0) ? 0 : part[t - 1];
#pragma unroll
    for (int j = 0; j < 4; j++) {
        if (base + j < n) row_ptr[base + j] = excl;
        excl += v[j];
    }
    if (t == NTHREADS - 1) bsums[blockIdx.x] = part[NTHREADS - 1];
}

__global__ void scan2(int* bsums, int nb) {
    if (threadIdx.x == 0 && blockIdx.x == 0) {
        int run = 0;
        for (int i = 0; i < nb; i++) { int v = bsums[i]; bsums[i] = run; run += v; }
    }
}

__global__ void scan3(int* row_ptr, const int* __restrict__ bsums, int n, int nE) {
    int i = blockIdx.x * NTHREADS + threadIdx.x;
    if (i < n) row_ptr[i] += bsums[i >> 10];
    if (i == 0) row_ptr[n] = nE;
}

// bucket: no atomics — position = row_ptr[dst] (L2-cached gather) + rank (precomputed)
// 4 edges/thread (one int4) -> 1563 blocks for occupancy.
__global__ void bucket(const int* __restrict__ ei, const int* __restrict__ rank,
                       const int* __restrict__ row_ptr, int* __restrict__ col, int nE) {
    int base = (blockIdx.x * NTHREADS + threadIdx.x) * 4;
    if (base + 3 < nE) {
        int4 s0 = *(const int4*)(ei + base);
        int4 d0 = *(const int4*)(ei + nE + base);
        int4 r0 = *(const int4*)(rank + base);
        col[row_ptr[d0.x] + r0.x] = s0.x;
        col[row_ptr[d0.y] + r0.y] = s0.y;
        col[row_ptr[d0.z] + r0.z] = s0.z;
        col[row_ptr[d0.w] + r0.w] = s0.w;
    } else {
        for (int j = 0; j < 4; j++) {
            int e = base + j;
            if (e < nE) col[row_ptr[ei[nE + e]] + rank[e]] = ei[e];
        }
    }
}

// ---------------- GEMM: T[r][c] = bf16( dis[r] * sum_k relu?(in[r][k]) * W[k][c] ) ----------------
__global__ __launch_bounds__(NTHREADS) void gemm64(
    const float* __restrict__ in, __hip_bfloat16* __restrict__ out,
    const float* __restrict__ W, const float* __restrict__ dis,
    int n_rows, int relu_in) {
    __shared__ __align__(16) float sW[64 * 64];
    __shared__ __align__(16) float sX[64 * 64];
    __shared__ float sD[64];
    int t = threadIdx.x;
    int row_base = blockIdx.x * 64;

    const float4* W4 = (const float4*)W;
    float4* sW4 = (float4*)sW;
#pragma unroll
    for (int i = 0; i < 4; i++) sW4[t + NTHREADS * i] = W4[t + NTHREADS * i];

    if (t < 64) {
        int r = row_base + t;
        sD[t] = (r < n_rows) ? dis[r] : 0.f;
    }

    float4* sX4 = (float4*)sX;
#pragma unroll
    for (int i = 0; i < 4; i++) {
        int idx = t + NTHREADS * i;
        int r = row_base + (idx >> 4);
        float4 v = make_float4(0.f, 0.f, 0.f, 0.f);
        if (r < n_rows) v = ((const float4*)(in + (size_t)r * 64))[idx & 15];
        if (relu_in) {
            v.x = fmaxf(v.x, 0.f); v.y = fmaxf(v.y, 0.f);
            v.z = fmaxf(v.z, 0.f); v.w = fmaxf(v.w, 0.f);
        }
        sX4[idx] = v;
    }
    __syncthreads();

    int c = t & 63;
    int r0 = t >> 6;
    float acc[16];
#pragma unroll
    for (int j = 0; j < 16; j++) acc[j] = 0.f;

    for (int k = 0; k < 64; k += 4) {
        float w0 = sW[(k + 0) * 64 + c];
        float w1 = sW[(k + 1) * 64 + c];
        float w2 = sW[(k + 2) * 64 + c];
        float w3 = sW[(k + 3) * 64 + c];
#pragma unroll
        for (int j = 0; j < 16; j++) {
            float4 xv = *(const float4*)(sX + (r0 + 4 * j) * 64 + k);
            acc[j] += xv.x * w0 + xv.y * w1 + xv.z * w2 + xv.w * w3;
        }
    }

#pragma unroll
    for (int j = 0; j < 16; j++) {
        int r = row_base + r0 + 4 * j;
        if (r < n_rows) out[(size_t)r * 64 + c] = __float2bfloat16(sD[r0 + 4 * j] * acc[j]);
    }
}

// ---------------- GCN aggregate: out[d] = bias + dis[d]*(T'[d] + sum_in T'[s]) ----------------
// 16 lanes per node; 8-deep gather unroll for latency hiding.
__global__ __launch_bounds__(NTHREADS) void gcn_aggregate(
    const __hip_bfloat16* __restrict__ T, float* __restrict__ out,
    const float* __restrict__ dis, const float* __restrict__ bias,
    const int* __restrict__ row_ptr, const int* __restrict__ col, int n) {
    int node = (blockIdx.x * NTHREADS + threadIdx.x) >> 4;
    int q = threadIdx.x & 15;
    if (node >= n) return;

    const ushort4* T4 = (const ushort4*)T;
    float4 acc = bf4_to_f4(T4[(size_t)node * 16 + q]);  // self term

    int e0 = row_ptr[node];
    int e1 = row_ptr[node + 1];
    int e = e0;
    for (; e + 7 < e1; e += 8) {
        int s0 = col[e],     s1 = col[e + 1], s2 = col[e + 2], s3 = col[e + 3];
        int s4 = col[e + 4], s5 = col[e + 5], s6 = col[e + 6], s7 = col[e + 7];
        float4 f0 = bf4_to_f4(T4[(size_t)s0 * 16 + q]);
        float4 f1 = bf4_to_f4(T4[(size_t)s1 * 16 + q]);
        float4 f2 = bf4_to_f4(T4[(size_t)s2 * 16 + q]);
        float4 f3 = bf4_to_f4(T4[(size_t)s3 * 16 + q]);
        float4 f4v = bf4_to_f4(T4[(size_t)s4 * 16 + q]);
        float4 f5 = bf4_to_f4(T4[(size_t)s5 * 16 + q]);
        float4 f6 = bf4_to_f4(T4[(size_t)s6 * 16 + q]);
        float4 f7 = bf4_to_f4(T4[(size_t)s7 * 16 + q]);
        acc.x += ((f0.x + f1.x) + (f2.x + f3.x)) + ((f4v.x + f5.x) + (f6.x + f7.x));
        acc.y += ((f0.y + f1.y) + (f2.y + f3.y)) + ((f4v.y + f5.y) + (f6.y + f7.y));
        acc.z += ((f0.z + f1.z) + (f2.z + f3.z)) + ((f4v.z + f5.z) + (f6.z + f7.z));
        acc.w += ((f0.w + f1.w) + (f2.w + f3.w)) + ((f4v.w + f5.w) + (f6.w + f7.w));
    }
    for (; e + 3 < e1; e += 4) {
        int s0 = col[e], s1 = col[e + 1], s2 = col[e + 2], s3 = col[e + 3];
        float4 f0 = bf4_to_f4(T4[(size_t)s0 * 16 + q]);
        float4 f1 = bf4_to_f4(T4[(size_t)s1 * 16 + q]);
        float4 f2 = bf4_to_f4(T4[(size_t)s2 * 16 + q]);
        float4 f3 = bf4_to_f4(T4[(size_t)s3 * 16 + q]);
        acc.x += (f0.x + f1.x) + (f2.x + f3.x);
        acc.y += (f0.y + f1.y) + (f2.y + f3.y);
        acc.z += (f0.z + f1.z) + (f2.z + f3.z);
        acc.w += (f0.w + f1.w) + (f2.w + f3.w);
    }
    for (; e < e1; e++) {
        float4 f0 = bf4_to_f4(T4[(size_t)col[e] * 16 + q]);
        acc.x += f0.x; acc.y += f0.y; acc.z += f0.z; acc.w += f0.w;
    }

    float dn = dis[node];
    float4 b = ((const float4*)bias)[q];
    float4 o;
    o.x = b.x + dn * acc.x;
    o.y = b.y + dn * acc.y;
    o.z = b.z + dn * acc.z;
    o.w = b.w + dn * acc.w;
    ((float4*)out)[(size_t)node * 16 + q] = o;
}

// ---------------- pooling: 128 nodes/block, register run-length, global atomics ----------------
__global__ __launch_bounds__(NTHREADS) void pool_kernel(
    const float* __restrict__ h, const int* __restrict__ gid,
    float* __restrict__ pooled, int n) {
    int t = threadIdx.x;
    int q = t & 15;
    int w = t >> 4;
    int base = blockIdx.x * 128;

    float4 racc = make_float4(0.f, 0.f, 0.f, 0.f);
    int cur = -1;
#pragma unroll
    for (int i = 0; i < 8; i++) {
        int node = base + i * 16 + w;
        if (node < n) {
            int g = gid[node];
            if (g != cur) {
                if (cur >= 0) {
                    float* p = pooled + cur * 64 + q * 4;
                    if (racc.x != 0.f) atomicAdd(p + 0, racc.x);
                    if (racc.y != 0.f) atomicAdd(p + 1, racc.y);
                    if (racc.z != 0.f) atomicAdd(p + 2, racc.z);
                    if (racc.w != 0.f) atomicAdd(p + 3, racc.w);
                }
                racc = make_float4(0.f, 0.f, 0.f, 0.f);
                cur = g;
            }
            float4 v = ((const float4*)h)[(size_t)node * 16 + q];
            racc.x += fmaxf(v.x, 0.f);
            racc.y += fmaxf(v.y, 0.f);
            racc.z += fmaxf(v.z, 0.f);
            racc.w += fmaxf(v.w, 0.f);
        }
    }
    if (cur >= 0) {
        float* p = pooled + cur * 64 + q * 4;
        if (racc.x != 0.f) atomicAdd(p + 0, racc.x);
        if (racc.y != 0.f) atomicAdd(p + 1, racc.y);
        if (racc.z != 0.f) atomicAdd(p + 2, racc.z);
        if (racc.w != 0.f) atomicAdd(p + 3, racc.w);
    }
}

// ---------------- head MLP (one block) ----------------
__global__ __launch_bounds__(NTHREADS) void head_kernel(
    const float* __restrict__ pooled, const float* __restrict__ gf,
    const float* __restrict__ glob_w, const float* __restrict__ glob_b,
    const float* __restrict__ lin1_w, const float* __restrict__ lin1_b,
    const float* __restrict__ lin2_w, const float* __restrict__ lin2_b,
    const float* __restrict__ lin3_w, const float* __restrict__ lin3_b,
    const float* __restrict__ lin4_w, const float* __restrict__ lin4_b,
    float* __restrict__ out) {
    __shared__ float gx[64 * 32];
    __shared__ float zA[64 * 64];
    __shared__ float zB[64 * 64];
    int t = threadIdx.x;

    for (int i = t; i < 64 * 32; i += NTHREADS) {
        int g = i >> 5, j = i & 31;
        float acc = glob_b[j];
        for (int k = 0; k < 32; k++) acc += gf[g * 32 + k] * glob_w[k * 32 + j];
        gx[i] = fmaxf(acc, 0.f);
    }
    for (int i = t; i < 4096; i += NTHREADS) {
        int g = i >> 6, j = i & 63;
        float acc = lin1_b[j];
        for (int k = 0; k < 64; k++) acc += pooled[g * 64 + k] * lin1_w[k * 64 + j];
        zA[i] = fmaxf(acc, 0.f);
    }
    __syncthreads();
    for (int i = t; i < 4096; i += NTHREADS) {
        int g = i >> 6, j = i & 63;
        float acc = lin2_b[j];
        for (int k = 0; k < 64; k++) acc += zA[g * 64 + k] * lin2_w[k * 64 + j];
        for (int k = 0; k < 32; k++) acc += gx[g * 32 + k] * lin2_w[(64 + k) * 64 + j];
        zB[i] = fmaxf(acc, 0.f);
    }
    __syncthreads();
    for (int i = t; i < 4096; i += NTHREADS) {
        int g = i >> 6, j = i & 63;
        float acc = lin3_b[j];
        for (int k = 0; k < 64; k++) acc += zB[g * 64 + k] * lin3_w[k * 64 + j];
        zA[i] = fmaxf(acc, 0.f);
    }
    __syncthreads();
    if (t < 64) {
        float acc = lin4_b[0];
        for (int k = 0; k < 64; k++) acc += zA[t * 64 + k] * lin4_w[k];
        out[t] = acc;
    }
}

extern "C" void kernel_launch(void* const* d_in, const int* in_sizes, int n_in,
                              void* d_out, int out_size, void* d_ws, size_t ws_size,
                              hipStream_t stream) {
    const float* x      = (const float*)d_in[0];
    const float* gf     = (const float*)d_in[1];
    const float* conv_w[3] = {(const float*)d_in[2], (const float*)d_in[4], (const float*)d_in[6]};
    const float* conv_b[3] = {(const float*)d_in[3], (const float*)d_in[5], (const float*)d_in[7]};
    const float* lin1_w = (const float*)d_in[8];
    const float* lin1_b = (const float*)d_in[9];
    const float* glob_w = (const float*)d_in[10];
    const float* glob_b = (const float*)d_in[11];
    const float* lin2_w = (const float*)d_in[12];
    const float* lin2_b = (const float*)d_in[13];
    const float* lin3_w = (const float*)d_in[14];
    const float* lin3_b = (const float*)d_in[15];
    const float* lin4_w = (const float*)d_in[16];
    const float* lin4_b = (const float*)d_in[17];
    const int* ei  = (const int*)d_in[18];
    const int* gid = (const int*)d_in[19];

    const int N = in_sizes[0] / 64;   // 100000
    const int E = in_sizes[18] / 2;   // 1600000

    // workspace layout (keep every segment 16B-aligned)
    char* ws = (char*)d_ws;
    float* dis     = (float*)ws;                 ws += (size_t)N * 4;
    float* pooled  = (float*)ws;                 ws += 4096 * 4;
    __hip_bfloat16* T = (__hip_bfloat16*)ws;     ws += (size_t)N * 64 * 2;
    float* A       = (float*)ws;                 ws += (size_t)N * 64 * 4;
    int*   degi    = (int*)ws;                   ws += (size_t)N * 4;
    int*   row_ptr = (int*)ws;                   ws += ((size_t)N + 4) * 4;
    int*   rank    = (int*)ws;                   ws += (size_t)E * 4;
    int*   col     = (int*)ws;                   ws += (size_t)E * 4;
    int*   bsums   = (int*)ws;                   ws += 512 * 4;

    const int nb_N  = (N + NTHREADS - 1) / NTHREADS;
    const int nb_E2 = (E / 2 + NTHREADS - 1) / NTHREADS;   // 2 edges/thread
    const int nb_E4 = (E / 4 + NTHREADS - 1) / NTHREADS;   // 4 edges/thread
    const int nb_sc = (N + 1023) / 1024;

    // ---- CSR build ----
    hipMemsetAsync(degi, 0, (size_t)N * 4, stream);
    hist_dst<<<nb_E2, NTHREADS, 0, stream>>>(degi, rank, ei, E);
    scan1<<<nb_sc, NTHREADS, 0, stream>>>(degi, row_ptr, bsums, dis, N);
    scan2<<<1, 64, 0, stream>>>(bsums, nb_sc);
    scan3<<<nb_N, NTHREADS, 0, stream>>>(row_ptr, bsums, N, E);
    bucket<<<nb_E4, NTHREADS, 0, stream>>>(ei, rank, row_ptr, col, E);

    const int gemm_blocks = (N + 63) / 64;
    const int agg_blocks  = (N * 16 + NTHREADS - 1) / NTHREADS;

    // layer 0: x -> T -> A
    gemm64<<<gemm_blocks, NTHREADS, 0, stream>>>(x, T, conv_w[0], dis, N, 0);
    gcn_aggregate<<<agg_blocks, NTHREADS, 0, stream>>>(T, A, dis, conv_b[0], row_ptr, col, N);

    // layer 1: relu(A) -> T -> A
    gemm64<<<gemm_blocks, NTHREADS, 0, stream>>>(A, T, conv_w[1], dis, N, 1);
    gcn_aggregate<<<agg_blocks, NTHREADS, 0, stream>>>(T, A, dis, conv_b[1], row_ptr, col, N);

    // layer 2: relu(A) -> T -> A
    gemm64<<<gemm_blocks, NTHREADS, 0, stream>>>(A, T, conv_w[2], dis, N, 1);
    gcn_aggregate<<<agg_blocks, NTHREADS, 0, stream>>>(T, A, dis, conv_b[2], row_ptr, col, N);

    // pooling (applies relu to conv2 output)
    hipMemsetAsync(pooled, 0, 4096 * 4, stream);
    pool_kernel<<<(N + 127) / 128, NTHREADS, 0, stream>>>(A, gid, pooled, N);

    // head MLP
    head_kernel<<<1, NTHREADS, 0, stream>>>(pooled, gf,
                                            glob_w, glob_b, lin1_w, lin1_b,
                                            lin2_w, lin2_b, lin3_w, lin3_b,
                                            lin4_w, lin4_b, (float*)d_out);
}

// Round 8
// 357.019 us; speedup vs baseline: 1.3628x; 1.0658x over previous
//
#include <hip/hip_runtime.h>
#include <hip/hip_bf16.h>

#define NTHREADS 256

typedef unsigned int uint32;

// accumulate 8 bf16 feats (packed in uint4) into two float4 accumulators
__device__ __forceinline__ void acc8(float4& A0, float4& A1, uint4 v) {
    A0.x += __uint_as_float(v.x << 16);
    A0.y += __uint_as_float(v.x & 0xffff0000u);
    A0.z += __uint_as_float(v.y << 16);
    A0.w += __uint_as_float(v.y & 0xffff0000u);
    A1.x += __uint_as_float(v.z << 16);
    A1.y += __uint_as_float(v.z & 0xffff0000u);
    A1.z += __uint_as_float(v.w << 16);
    A1.w += __uint_as_float(v.w & 0xffff0000u);
}

// ---------------- CSR build ----------------
__global__ void hist_dst(int* degi, int* __restrict__ rank,
                         const int* __restrict__ ei, int nE) {
    int base = (blockIdx.x * NTHREADS + threadIdx.x) * 2;
    if (base + 1 < nE) {
        int2 d = *(const int2*)(ei + nE + base);
        int2 r;
        r.x = atomicAdd(&degi[d.x], 1);
        r.y = atomicAdd(&degi[d.y], 1);
        *(int2*)(rank + base) = r;
    } else if (base < nE) {
        rank[base] = atomicAdd(&degi[ei[nE + base]], 1);
    }
}

__global__ __launch_bounds__(NTHREADS) void scan1(const int* __restrict__ degi,
                                                  int* row_ptr, int* bsums,
                                                  float* dis, int n) {
    __shared__ int part[NTHREADS];
    int t = threadIdx.x;
    int base = blockIdx.x * 1024 + t * 4;
    int v[4];
    int s = 0;
#pragma unroll
    for (int j = 0; j < 4; j++) {
        v[j] = (base + j < n) ? degi[base + j] : 0;
        s += v[j];
    }
#pragma unroll
    for (int j = 0; j < 4; j++) {
        if (base + j < n) dis[base + j] = rsqrtf(1.0f + (float)v[j]);
    }
    part[t] = s;
    __syncthreads();
    for (int off = 1; off < NTHREADS; off <<= 1) {
        int x = (t >= off) ? part[t - off] : 0;
        __syncthreads();
        part[t] += x;
        __syncthreads();
    }
    int excl = (t == 0) ? 0 : part[t - 1];
#pragma unroll
    for (int j = 0; j < 4; j++) {
        if (base + j < n) row_ptr[base + j] = excl;
        excl += v[j];
    }
    if (t == NTHREADS - 1) bsums[blockIdx.x] = part[NTHREADS - 1];
}

// parallel exclusive scan of bsums (nb <= 256)
__global__ __launch_bounds__(NTHREADS) void scan2(int* bsums, int nb) {
    __shared__ int sm[NTHREADS];
    int t = threadIdx.x;
    int v = (t < nb) ? bsums[t] : 0;
    sm[t] = v;
    __syncthreads();
    for (int off = 1; off < NTHREADS; off <<= 1) {
        int a = (t >= off) ? sm[t - off] : 0;
        __syncthreads();
        sm[t] += a;
        __syncthreads();
    }
    if (t < nb) bsums[t] = (t == 0) ? 0 : sm[t - 1];
}

__global__ void scan3(int* row_ptr, const int* __restrict__ bsums, int n, int nE) {
    int i = blockIdx.x * NTHREADS + threadIdx.x;
    if (i < n) row_ptr[i] += bsums[i >> 10];
    if (i == 0) row_ptr[n] = nE;
}

// ---------------- GEMM body: T[r][c] = bf16( dis[r] * sum_k relu?(in[r][k]) * W[k][c] ) ----------------
__device__ __forceinline__ void gemm_body(
    const float* __restrict__ in, __hip_bfloat16* __restrict__ out,
    const float* __restrict__ W, const float* __restrict__ dis,
    int n_rows, int relu_in, int row_base,
    float* sW, float* sX, float* sD) {
    int t = threadIdx.x;

    const float4* W4 = (const float4*)W;
    float4* sW4 = (float4*)sW;
#pragma unroll
    for (int i = 0; i < 4; i++) sW4[t + NTHREADS * i] = W4[t + NTHREADS * i];

    if (t < 64) {
        int r = row_base + t;
        sD[t] = (r < n_rows) ? dis[r] : 0.f;
    }

    float4* sX4 = (float4*)sX;
#pragma unroll
    for (int i = 0; i < 4; i++) {
        int idx = t + NTHREADS * i;
        int r = row_base + (idx >> 4);
        float4 v = make_float4(0.f, 0.f, 0.f, 0.f);
        if (r < n_rows) v = ((const float4*)(in + (size_t)r * 64))[idx & 15];
        if (relu_in) {
            v.x = fmaxf(v.x, 0.f); v.y = fmaxf(v.y, 0.f);
            v.z = fmaxf(v.z, 0.f); v.w = fmaxf(v.w, 0.f);
        }
        sX4[idx] = v;
    }
    __syncthreads();

    int c = t & 63;
    int r0 = t >> 6;
    float acc[16];
#pragma unroll
    for (int j = 0; j < 16; j++) acc[j] = 0.f;

    for (int k = 0; k < 64; k += 4) {
        float w0 = sW[(k + 0) * 64 + c];
        float w1 = sW[(k + 1) * 64 + c];
        float w2 = sW[(k + 2) * 64 + c];
        float w3 = sW[(k + 3) * 64 + c];
#pragma unroll
        for (int j = 0; j < 16; j++) {
            float4 xv = *(const float4*)(sX + (r0 + 4 * j) * 64 + k);
            acc[j] += xv.x * w0 + xv.y * w1 + xv.z * w2 + xv.w * w3;
        }
    }

#pragma unroll
    for (int j = 0; j < 16; j++) {
        int r = row_base + r0 + 4 * j;
        if (r < n_rows) out[(size_t)r * 64 + c] = __float2bfloat16(sD[r0 + 4 * j] * acc[j]);
    }
}

// ---------------- fused: layer-0 GEMM (blocks first) + atomic-free bucket (blocks after) ----------------
__global__ __launch_bounds__(NTHREADS) void gemm0_bucket(
    const float* __restrict__ in, __hip_bfloat16* __restrict__ T,
    const float* __restrict__ W, const float* __restrict__ dis,
    const int* __restrict__ ei, const int* __restrict__ rank,
    const int* __restrict__ row_ptr, int* __restrict__ col,
    int n_rows, int nE, int nGemmBlocks) {
    __shared__ __align__(16) float sW[64 * 64];
    __shared__ __align__(16) float sX[64 * 64];
    __shared__ float sD[64];

    if ((int)blockIdx.x < nGemmBlocks) {
        gemm_body(in, T, W, dis, n_rows, 0, blockIdx.x * 64, sW, sX, sD);
        return;
    }

    int bb = blockIdx.x - nGemmBlocks;
    int base = (bb * NTHREADS + threadIdx.x) * 4;
    if (base + 3 < nE) {
        int4 s0 = *(const int4*)(ei + base);
        int4 d0 = *(const int4*)(ei + nE + base);
        int4 r0 = *(const int4*)(rank + base);
        col[row_ptr[d0.x] + r0.x] = s0.x;
        col[row_ptr[d0.y] + r0.y] = s0.y;
        col[row_ptr[d0.z] + r0.z] = s0.z;
        col[row_ptr[d0.w] + r0.w] = s0.w;
    } else {
        for (int j = 0; j < 4; j++) {
            int e = base + j;
            if (e < nE) col[row_ptr[ei[nE + e]] + rank[e]] = ei[e];
        }
    }
}

// ---------------- standalone GEMM (layers 1,2) ----------------
__global__ __launch_bounds__(NTHREADS) void gemm64(
    const float* __restrict__ in, __hip_bfloat16* __restrict__ out,
    const float* __restrict__ W, const float* __restrict__ dis,
    int n_rows, int relu_in) {
    __shared__ __align__(16) float sW[64 * 64];
    __shared__ __align__(16) float sX[64 * 64];
    __shared__ float sD[64];
    gemm_body(in, out, W, dis, n_rows, relu_in, blockIdx.x * 64, sW, sX, sD);
}

// ---------------- GCN aggregate: out[d] = bias + dis[d]*(T'[d] + sum_in T'[s]) ----------------
// 8 lanes per node (16B uint4 loads) -> 8 node-chains per wave; 8-deep unroll.
__global__ __launch_bounds__(NTHREADS) void gcn_aggregate(
    const __hip_bfloat16* __restrict__ T, float* __restrict__ out,
    const float* __restrict__ dis, const float* __restrict__ bias,
    const int* __restrict__ row_ptr, const int* __restrict__ col, int n) {
    int node = (blockIdx.x * NTHREADS + threadIdx.x) >> 3;
    int q = threadIdx.x & 7;   // 16B chunk index within 128B row
    if (node >= n) return;

    const uint4* T8 = (const uint4*)T;
    float4 a0 = make_float4(0.f, 0.f, 0.f, 0.f);
    float4 a1 = make_float4(0.f, 0.f, 0.f, 0.f);
    acc8(a0, a1, T8[(size_t)node * 8 + q]);  // self term

    int e0 = row_ptr[node];
    int e1 = row_ptr[node + 1];
    int e = e0;
    for (; e + 7 < e1; e += 8) {
        int s0 = col[e],     s1 = col[e + 1], s2 = col[e + 2], s3 = col[e + 3];
        int s4 = col[e + 4], s5 = col[e + 5], s6 = col[e + 6], s7 = col[e + 7];
        uint4 v0 = T8[(size_t)s0 * 8 + q];
        uint4 v1 = T8[(size_t)s1 * 8 + q];
        uint4 v2 = T8[(size_t)s2 * 8 + q];
        uint4 v3 = T8[(size_t)s3 * 8 + q];
        uint4 v4 = T8[(size_t)s4 * 8 + q];
        uint4 v5 = T8[(size_t)s5 * 8 + q];
        uint4 v6 = T8[(size_t)s6 * 8 + q];
        uint4 v7 = T8[(size_t)s7 * 8 + q];
        acc8(a0, a1, v0); acc8(a0, a1, v1); acc8(a0, a1, v2); acc8(a0, a1, v3);
        acc8(a0, a1, v4); acc8(a0, a1, v5); acc8(a0, a1, v6); acc8(a0, a1, v7);
    }
    for (; e + 3 < e1; e += 4) {
        int s0 = col[e], s1 = col[e + 1], s2 = col[e + 2], s3 = col[e + 3];
        uint4 v0 = T8[(size_t)s0 * 8 + q];
        uint4 v1 = T8[(size_t)s1 * 8 + q];
        uint4 v2 = T8[(size_t)s2 * 8 + q];
        uint4 v3 = T8[(size_t)s3 * 8 + q];
        acc8(a0, a1, v0); acc8(a0, a1, v1); acc8(a0, a1, v2); acc8(a0, a1, v3);
    }
    for (; e < e1; e++) {
        acc8(a0, a1, T8[(size_t)col[e] * 8 + q]);
    }

    float dn = dis[node];
    float4 b0 = ((const float4*)bias)[q * 2];
    float4 b1 = ((const float4*)bias)[q * 2 + 1];
    float4 o0, o1;
    o0.x = b0.x + dn * a0.x; o0.y = b0.y + dn * a0.y;
    o0.z = b0.z + dn * a0.z; o0.w = b0.w + dn * a0.w;
    o1.x = b1.x + dn * a1.x; o1.y = b1.y + dn * a1.y;
    o1.z = b1.z + dn * a1.z; o1.w = b1.w + dn * a1.w;
    float4* orow = (float4*)out + (size_t)node * 16 + q * 2;
    orow[0] = o0;
    orow[1] = o1;
}

// ---------------- pooling: 128 nodes/block, register run-length, global atomics ----------------
__global__ __launch_bounds__(NTHREADS) void pool_kernel(
    const float* __restrict__ h, const int* __restrict__ gid,
    float* __restrict__ pooled, int n) {
    int t = threadIdx.x;
    int q = t & 15;
    int w = t >> 4;
    int base = blockIdx.x * 128;

    float4 racc = make_float4(0.f, 0.f, 0.f, 0.f);
    int cur = -1;
#pragma unroll
    for (int i = 0; i < 8; i++) {
        int node = base + i * 16 + w;
        if (node < n) {
            int g = gid[node];
            if (g != cur) {
                if (cur >= 0) {
                    float* p = pooled + cur * 64 + q * 4;
                    if (racc.x != 0.f) atomicAdd(p + 0, racc.x);
                    if (racc.y != 0.f) atomicAdd(p + 1, racc.y);
                    if (racc.z != 0.f) atomicAdd(p + 2, racc.z);
                    if (racc.w != 0.f) atomicAdd(p + 3, racc.w);
                }
                racc = make_float4(0.f, 0.f, 0.f, 0.f);
                cur = g;
            }
            float4 v = ((const float4*)h)[(size_t)node * 16 + q];
            racc.x += fmaxf(v.x, 0.f);
            racc.y += fmaxf(v.y, 0.f);
            racc.z += fmaxf(v.z, 0.f);
            racc.w += fmaxf(v.w, 0.f);
        }
    }
    if (cur >= 0) {
        float* p = pooled + cur * 64 + q * 4;
        if (racc.x != 0.f) atomicAdd(p + 0, racc.x);
        if (racc.y != 0.f) atomicAdd(p + 1, racc.y);
        if (racc.z != 0.f) atomicAdd(p + 2, racc.z);
        if (racc.w != 0.f) atomicAdd(p + 3, racc.w);
    }
}

// ---------------- head MLP (one block) ----------------
__global__ __launch_bounds__(NTHREADS) void head_kernel(
    const float* __restrict__ pooled, const float* __restrict__ gf,
    const float* __restrict__ glob_w, const float* __restrict__ glob_b,
    const float* __restrict__ lin1_w, const float* __restrict__ lin1_b,
    const float* __restrict__ lin2_w, const float* __restrict__ lin2_b,
    const float* __restrict__ lin3_w, const float* __restrict__ lin3_b,
    const float* __restrict__ lin4_w, const float* __restrict__ lin4_b,
    float* __restrict__ out) {
    __shared__ float gx[64 * 32];
    __shared__ float zA[64 * 64];
    __shared__ float zB[64 * 64];
    int t = threadIdx.x;

    for (int i = t; i < 64 * 32; i += NTHREADS) {
        int g = i >> 5, j = i & 31;
        float acc = glob_b[j];
        for (int k = 0; k < 32; k++) acc += gf[g * 32 + k] * glob_w[k * 32 + j];
        gx[i] = fmaxf(acc, 0.f);
    }
    for (int i = t; i < 4096; i += NTHREADS) {
        int g = i >> 6, j = i & 63;
        float acc = lin1_b[j];
        for (int k = 0; k < 64; k++) acc += pooled[g * 64 + k] * lin1_w[k * 64 + j];
        zA[i] = fmaxf(acc, 0.f);
    }
    __syncthreads();
    for (int i = t; i < 4096; i += NTHREADS) {
        int g = i >> 6, j = i & 63;
        float acc = lin2_b[j];
        for (int k = 0; k < 64; k++) acc += zA[g * 64 + k] * lin2_w[k * 64 + j];
        for (int k = 0; k < 32; k++) acc += gx[g * 32 + k] * lin2_w[(64 + k) * 64 + j];
        zB[i] = fmaxf(acc, 0.f);
    }
    __syncthreads();
    for (int i = t; i < 4096; i += NTHREADS) {
        int g = i >> 6, j = i & 63;
        float acc = lin3_b[j];
        for (int k = 0; k < 64; k++) acc += zB[g * 64 + k] * lin3_w[k * 64 + j];
        zA[i] = fmaxf(acc, 0.f);
    }
    __syncthreads();
    if (t < 64) {
        float acc = lin4_b[0];
        for (int k = 0; k < 64; k++) acc += zA[t * 64 + k] * lin4_w[k];
        out[t] = acc;
    }
}

extern "C" void kernel_launch(void* const* d_in, const int* in_sizes, int n_in,
                              void* d_out, int out_size, void* d_ws, size_t ws_size,
                              hipStream_t stream) {
    const float* x      = (const float*)d_in[0];
    const float* gf     = (const float*)d_in[1];
    const float* conv_w[3] = {(const float*)d_in[2], (const float*)d_in[4], (const float*)d_in[6]};
    const float* conv_b[3] = {(const float*)d_in[3], (const float*)d_in[5], (const float*)d_in[7]};
    const float* lin1_w = (const float*)d_in[8];
    const float* lin1_b = (const float*)d_in[9];
    const float* glob_w = (const float*)d_in[10];
    const float* glob_b = (const float*)d_in[11];
    const float* lin2_w = (const float*)d_in[12];
    const float* lin2_b = (const float*)d_in[13];
    const float* lin3_w = (const float*)d_in[14];
    const float* lin3_b = (const float*)d_in[15];
    const float* lin4_w = (const float*)d_in[16];
    const float* lin4_b = (const float*)d_in[17];
    const int* ei  = (const int*)d_in[18];
    const int* gid = (const int*)d_in[19];

    const int N = in_sizes[0] / 64;   // 100000
    const int E = in_sizes[18] / 2;   // 1600000

    // workspace layout (keep every segment 16B-aligned)
    char* ws = (char*)d_ws;
    float* dis     = (float*)ws;                 ws += (size_t)N * 4;
    float* pooled  = (float*)ws;                 ws += 4096 * 4;
    __hip_bfloat16* T = (__hip_bfloat16*)ws;     ws += (size_t)N * 64 * 2;
    float* A       = (float*)ws;                 ws += (size_t)N * 64 * 4;
    int*   degi    = (int*)ws;                   ws += (size_t)N * 4;
    int*   row_ptr = (int*)ws;                   ws += ((size_t)N + 4) * 4;
    int*   rank    = (int*)ws;                   ws += (size_t)E * 4;
    int*   col     = (int*)ws;                   ws += (size_t)E * 4;
    int*   bsums   = (int*)ws;                   ws += 512 * 4;

    const int nb_N  = (N + NTHREADS - 1) / NTHREADS;
    const int nb_E2 = (E / 2 + NTHREADS - 1) / NTHREADS;   // 2 edges/thread
    const int nb_E4 = (E / 4 + NTHREADS - 1) / NTHREADS;   // 4 edges/thread
    const int nb_sc = (N + 1023) / 1024;

    const int gemm_blocks = (N + 63) / 64;
    const int agg_blocks  = (N * 8 + NTHREADS - 1) / NTHREADS;

    // ---- CSR build ----
    hipMemsetAsync(degi, 0, (size_t)N * 4, stream);
    hist_dst<<<nb_E2, NTHREADS, 0, stream>>>(degi, rank, ei, E);
    scan1<<<nb_sc, NTHREADS, 0, stream>>>(degi, row_ptr, bsums, dis, N);
    scan2<<<1, NTHREADS, 0, stream>>>(bsums, nb_sc);
    scan3<<<nb_N, NTHREADS, 0, stream>>>(row_ptr, bsums, N, E);

    // layer 0 GEMM (blocks first) fused with bucket (blocks after)
    gemm0_bucket<<<gemm_blocks + nb_E4, NTHREADS, 0, stream>>>(
        x, T, conv_w[0], dis, ei, rank, row_ptr, col, N, E, gemm_blocks);
    gcn_aggregate<<<agg_blocks, NTHREADS, 0, stream>>>(T, A, dis, conv_b[0], row_ptr, col, N);

    // layer 1: relu(A) -> T -> A
    gemm64<<<gemm_blocks, NTHREADS, 0, stream>>>(A, T, conv_w[1], dis, N, 1);
    gcn_aggregate<<<agg_blocks, NTHREADS, 0, stream>>>(T, A, dis, conv_b[1], row_ptr, col, N);

    // layer 2: relu(A) -> T -> A
    gemm64<<<gemm_blocks, NTHREADS, 0, stream>>>(A, T, conv_w[2], dis, N, 1);
    gcn_aggregate<<<agg_blocks, NTHREADS, 0, stream>>>(T, A, dis, conv_b[2], row_ptr, col, N);

    // pooling (applies relu to conv2 output)
    hipMemsetAsync(pooled, 0, 4096 * 4, stream);
    pool_kernel<<<(N + 127) / 128, NTHREADS, 0, stream>>>(A, gid, pooled, N);

    // head MLP
    head_kernel<<<1, NTHREADS, 0, stream>>>(pooled, gf,
                                            glob_w, glob_b, lin1_w, lin1_b,
                                            lin2_w, lin2_b, lin3_w, lin3_b,
                                            lin4_w, lin4_b, (float*)d_out);
}